// Round 1
// baseline (439.754 us; speedup 1.0000x reference)
//
#include <hip/hip_runtime.h>
#include <hip/hip_bf16.h>
#include <math.h>

#define EMB 1024
#define BATCH 32
#define SEQ 1024
#define PROJ 128
#define J2 256          // 2*PROJ
#define KT 32           // k-tile
#define RB 64           // rows per block
#define AST 36          // A lds stride (floats), 16B-aligned stores
#define WST 33          // W lds stride (floats), conflict-free reads

// ---------------- Kernel 1: qk = ctx @ W^T + bias --------------------------
// Rows in s-major order: m2 = s*B + b, so the context row is contiguous at
// ctx + m2*EMB. Output goes to qk[b][s][j] = qk[((b<<10)+s)*256 + j].
__global__ __launch_bounds__(256) void gemm_qk(const float* __restrict__ ctx,
                                               const float* __restrict__ W,
                                               const float* __restrict__ bias,
                                               float* __restrict__ qk) {
    __shared__ float As[RB * AST];   // [r][e], 9216 B
    __shared__ float Ws[J2 * WST];   // [j][e], 33792 B
    const int t  = threadIdx.x;
    const int tx = t & 31;           // col group: cols tx + 32*i
    const int ty = t >> 5;           // row group: rows ty*8 + rr
    const int m0 = blockIdx.x * RB;

    float bv[8];
    #pragma unroll
    for (int i = 0; i < 8; i++) bv[i] = bias[tx + (i << 5)];

    float acc[8][8];
    #pragma unroll
    for (int rr = 0; rr < 8; rr++)
        #pragma unroll
        for (int i = 0; i < 8; i++) acc[rr][i] = 0.f;

    const float4* ctx4 = (const float4*)ctx;
    const float4* W4   = (const float4*)W;

    for (int k0 = 0; k0 < EMB; k0 += KT) {
        const int k4 = k0 >> 2;
        // stage A tile: 64 rows x 32 floats = 512 float4, 2/thread
        #pragma unroll
        for (int q = 0; q < 2; q++) {
            int fi = q * 256 + t;            // 0..511
            int r  = fi >> 3, eq = fi & 7;
            float4 v = ctx4[(size_t)(m0 + r) * 256 + k4 + eq];
            *(float4*)(&As[r * AST + (eq << 2)]) = v;
        }
        // stage W tile: 256 j x 32 floats = 2048 float4, 8/thread
        #pragma unroll
        for (int q = 0; q < 8; q++) {
            int fi = q * 256 + t;            // 0..2047
            int j  = fi >> 3, eq = fi & 7;
            float4 v = W4[(size_t)j * 256 + k4 + eq];
            float* dst = &Ws[j * WST + (eq << 2)];
            dst[0] = v.x; dst[1] = v.y; dst[2] = v.z; dst[3] = v.w;
        }
        __syncthreads();
        #pragma unroll 8
        for (int e = 0; e < KT; e++) {
            float a[8], w[8];
            #pragma unroll
            for (int rr = 0; rr < 8; rr++) a[rr] = As[(ty * 8 + rr) * AST + e];
            #pragma unroll
            for (int i = 0; i < 8; i++)  w[i]  = Ws[(tx + (i << 5)) * WST + e];
            #pragma unroll
            for (int rr = 0; rr < 8; rr++)
                #pragma unroll
                for (int i = 0; i < 8; i++) acc[rr][i] += a[rr] * w[i];
        }
        __syncthreads();
    }

    #pragma unroll
    for (int rr = 0; rr < 8; rr++) {
        int m2 = m0 + ty * 8 + rr;
        int s = m2 >> 5, b = m2 & 31;      // m2 = s*B + b
        float* orow = qk + (size_t)((b << 10) + s) * J2;
        #pragma unroll
        for (int i = 0; i < 8; i++) orow[tx + (i << 5)] = acc[rr][i] + bv[i];
    }
}

// ---------------- Kernel 2: neighbor dot products --------------------------
// fwd[b,s] = q[b,s].k[b,s+1]/EMB ; bwd[b,s] = q[b,s+1].k[b,s]/EMB (s<S-1)
__global__ __launch_bounds__(256) void scores(const float* __restrict__ qk,
                                              float* __restrict__ fwd,
                                              float* __restrict__ bwd) {
    int wave = threadIdx.x >> 6, lane = threadIdx.x & 63;
    int idx = blockIdx.x * 4 + wave;       // idx = b*SEQ + s
    int s = idx & (SEQ - 1);
    if (s == SEQ - 1) return;
    const float* row0 = qk + (size_t)idx * J2;
    const float* row1 = row0 + J2;
    float f = row0[lane] * row1[128 + lane] + row0[64 + lane] * row1[192 + lane];
    float w = row1[lane] * row0[128 + lane] + row1[64 + lane] * row0[192 + lane];
    #pragma unroll
    for (int off = 32; off; off >>= 1) {
        f += __shfl_xor(f, off);
        w += __shfl_xor(w, off);
    }
    if (lane == 0) {
        fwd[idx] = f * (1.f / 1024.f);
        bwd[idx] = w * (1.f / 1024.f);
    }
}

// ---------------- Kernel 3: softmax, neighbor_attn, log, prefix-sum --------
__global__ __launch_bounds__(1024) void neighbor(const float* __restrict__ fwd,
                                                 const float* __restrict__ bwd,
                                                 const float* __restrict__ prior,
                                                 const int* __restrict__ mask,
                                                 float* __restrict__ out_n,
                                                 float* __restrict__ csp) {
    int b = blockIdx.x, s = threadIdx.x;
    __shared__ float p1s[SEQ];
    __shared__ float buf[2][SEQ];
    int base = b << 10;
    int rolled = mask[base + ((s + 1) & (SEQ - 1))];
    float c0 = (s < SEQ - 1) ? fwd[base + s] : -INFINITY;
    if (rolled) c0 = -INFINITY;
    float c1 = (s > 0) ? bwd[base + s - 1] : -INFINITY;
    float m = fmaxf(c0, c1);
    float e0 = expf(c0 - m), e1 = expf(c1 - m);
    float inv = 1.f / (e0 + e1);
    float p0 = e0 * inv, p1 = e1 * inv;
    p1s[s] = p1;
    __syncthreads();
    // flattened roll: shift at s=SEQ-1 picks prob[b+1 (or 0),0,1] == 0 always
    float shift = (s < SEQ - 1) ? p1s[s + 1] : 0.f;
    float p = sqrtf(p0 * shift + 1e-6f);
    float pr = prior[base + s];
    float na = pr + (1.f - pr) * p;
    out_n[base + s] = na;
    float lp = logf(na);
    if (rolled) lp = 0.f;
    buf[0][s] = lp;
    __syncthreads();
    int cur = 0;
    for (int off = 1; off < SEQ; off <<= 1) {
        float v = buf[cur][s];
        if (s >= off) v += buf[cur][s - off];
        buf[cur ^ 1][s] = v;
        __syncthreads();
        cur ^= 1;
    }
    csp[base + s] = (s == 0) ? 0.f : buf[cur][s - 1];   // exclusive prefix sum
}

// ---------------- Kernel 4: constituent_attn ------------------------------
// out[b,i,j] = (i==j) ? 0 : exp(csp[b,max(i,j)] - csp[b,min(i,j)])
__global__ __launch_bounds__(256) void outk(const float* __restrict__ csp,
                                            float* __restrict__ out) {
    int bi = blockIdx.x;                 // b*SEQ + i
    int b = bi >> 10, i = bi & (SEQ - 1);
    const float* crow = csp + (b << 10);
    float ci = crow[i];
    int t = threadIdx.x;
    float4 cj = ((const float4*)crow)[t];
    int j0 = t << 2;
    float4 r;
    {
        int j = j0 + 0;
        r.x = (j == i) ? 0.f : expf((j > i) ? (cj.x - ci) : (ci - cj.x));
        j = j0 + 1;
        r.y = (j == i) ? 0.f : expf((j > i) ? (cj.y - ci) : (ci - cj.y));
        j = j0 + 2;
        r.z = (j == i) ? 0.f : expf((j > i) ? (cj.z - ci) : (ci - cj.z));
        j = j0 + 3;
        r.w = (j == i) ? 0.f : expf((j > i) ? (cj.w - ci) : (ci - cj.w));
    }
    ((float4*)(out + (size_t)bi * SEQ))[t] = r;
}

extern "C" void kernel_launch(void* const* d_in, const int* in_sizes, int n_in,
                              void* d_out, int out_size, void* d_ws, size_t ws_size,
                              hipStream_t stream) {
    (void)in_sizes; (void)n_in; (void)out_size; (void)ws_size;
    const float* ctx   = (const float*)d_in[0];   // [S, B, E]
    const float* prior = (const float*)d_in[1];   // [B, S]
    const int*   mask  = (const int*)d_in[2];     // [B, S]
    const float* W     = (const float*)d_in[3];   // [256, 1024]
    const float* bias  = (const float*)d_in[4];   // [256]
    float* out = (float*)d_out;
    float* ws  = (float*)d_ws;

    float* qk  = ws;                              // B*S*256 = 8388608 floats
    float* fwd = ws + 8388608;                    // B*S
    float* bwd = fwd + 32768;                     // B*S
    float* csp = bwd + 32768;                     // B*S
    float* out_n = out + (size_t)BATCH * SEQ * SEQ;

    gemm_qk <<<(BATCH * SEQ) / RB, 256, 0, stream>>>(ctx, W, bias, qk);
    scores  <<<(BATCH * SEQ) / 4, 256, 0, stream>>>(qk, fwd, bwd);
    neighbor<<<BATCH, 1024, 0, stream>>>(fwd, bwd, prior, mask, out_n, csp);
    outk    <<<BATCH * SEQ, 256, 0, stream>>>(csp, out);
}

// Round 2
// 275.958 us; speedup vs baseline: 1.5936x; 1.5936x over previous
//
#include <hip/hip_runtime.h>
#include <hip/hip_bf16.h>
#include <math.h>

#define EMB 1024
#define BATCH 32
#define SEQ 1024
#define J2 256          // 2*PROJ
#define BM 128
#define BN 128
#define BK 64

typedef __attribute__((ext_vector_type(8))) short short8;
typedef __attribute__((ext_vector_type(4))) float f32x4;
typedef const __attribute__((address_space(1))) void gvoid;
typedef __attribute__((address_space(3))) void lvoid;

union Pack8 { short8 s; __hip_bfloat16 h[8]; };

// ---------------- Kernel 0: convert W fp32 -> bf16 -------------------------
__global__ __launch_bounds__(256) void convw(const float* __restrict__ W,
                                             __hip_bfloat16* __restrict__ Wb) {
    int i = blockIdx.x * 256 + threadIdx.x;          // 0 .. 65535, 4 floats each
    float4 v = ((const float4*)W)[i];
    __hip_bfloat16 h[4];
    h[0] = __float2bfloat16(v.x); h[1] = __float2bfloat16(v.y);
    h[2] = __float2bfloat16(v.z); h[3] = __float2bfloat16(v.w);
    *(short4*)&Wb[i * 4] = *(short4*)h;
}

// ---------------- Kernel 1: qk = ctx @ W^T + bias (bf16 MFMA) --------------
// A rows m = s*B + b (ctx row-major [S,B,E]); output qk[((b<<10)+s)*256 + n].
__global__ __launch_bounds__(256) void gemm_mfma(const float* __restrict__ ctx,
                                                 const __hip_bfloat16* __restrict__ Wb,
                                                 const float* __restrict__ bias,
                                                 float* __restrict__ qk) {
    __shared__ __align__(16) __hip_bfloat16 As[BM * BK];   // 16 KB, row-major, no pad
    __shared__ __align__(16) __hip_bfloat16 Bs[BN * BK];   // 16 KB
    const int t = threadIdx.x;
    const int lane = t & 63, w = t >> 6;
    const int n0 = (blockIdx.x & 1) * BN;
    const int m0 = (blockIdx.x >> 1) * BM;
    const int wm = (w & 1) * 64, wn = (w >> 1) * 64;
    const int lm = lane & 15, lq = lane >> 4;

    f32x4 acc[4][4] = {};

    float bv[4];
    #pragma unroll
    for (int ni = 0; ni < 4; ni++) bv[ni] = bias[n0 + wn + ni * 16 + lm];

    const float4* ctx4 = (const float4*)ctx;

    for (int k0 = 0; k0 < EMB; k0 += BK) {
        // ---- stage B: global_load_lds, 4 x 16B per thread -----------------
        #pragma unroll
        for (int c = 0; c < 4; c++) {
            int li = c * 256 + t;                  // 16B chunk id, 0..1023
            int row = li >> 3, k8 = li & 7;
            const __hip_bfloat16* g = Wb + (size_t)(n0 + row) * EMB + k0 + k8 * 8;
            __hip_bfloat16* l = &Bs[(c * 256 + w * 64) * 8];  // wave-uniform base
            __builtin_amdgcn_global_load_lds((gvoid*)g, (lvoid*)l, 16, 0, 0);
        }
        // ---- stage A: fp32 load + cvt -> bf16 LDS, 8 floats per chunk -----
        const int k4 = k0 >> 2;
        #pragma unroll
        for (int c = 0; c < 4; c++) {
            int li = c * 256 + t;                  // 8-float group id, 0..1023
            int row = li >> 3, k8 = li & 7;
            float4 v0 = ctx4[(size_t)(m0 + row) * 256 + k4 + k8 * 2];
            float4 v1 = ctx4[(size_t)(m0 + row) * 256 + k4 + k8 * 2 + 1];
            Pack8 p;
            p.h[0] = __float2bfloat16(v0.x); p.h[1] = __float2bfloat16(v0.y);
            p.h[2] = __float2bfloat16(v0.z); p.h[3] = __float2bfloat16(v0.w);
            p.h[4] = __float2bfloat16(v1.x); p.h[5] = __float2bfloat16(v1.y);
            p.h[6] = __float2bfloat16(v1.z); p.h[7] = __float2bfloat16(v1.w);
            *(short8*)&As[row * BK + k8 * 8] = p.s;
        }
        __syncthreads();
        // ---- MFMA over the two K=32 halves --------------------------------
        #pragma unroll
        for (int kk = 0; kk < BK; kk += 32) {
            short8 af[4], bfr[4];
            #pragma unroll
            for (int i = 0; i < 4; i++) {
                af[i]  = *(const short8*)&As[(wm + i * 16 + lm) * BK + kk + lq * 8];
                bfr[i] = *(const short8*)&Bs[(wn + i * 16 + lm) * BK + kk + lq * 8];
            }
            #pragma unroll
            for (int mi = 0; mi < 4; mi++)
                #pragma unroll
                for (int ni = 0; ni < 4; ni++)
                    acc[mi][ni] = __builtin_amdgcn_mfma_f32_16x16x32_bf16(
                        af[mi], bfr[ni], acc[mi][ni], 0, 0, 0);
        }
        __syncthreads();
    }

    // ---- epilogue: D row = m (A row), col = n; add bias -------------------
    #pragma unroll
    for (int mi = 0; mi < 4; mi++) {
        #pragma unroll
        for (int r = 0; r < 4; r++) {
            int m = m0 + wm + mi * 16 + lq * 4 + r;
            int s = m >> 5, b = m & 31;
            float* orow = qk + (size_t)((b << 10) + s) * J2;
            #pragma unroll
            for (int ni = 0; ni < 4; ni++) {
                int n = n0 + wn + ni * 16 + lm;
                orow[n] = acc[mi][ni][r] + bv[ni];
            }
        }
    }
}

// ---------------- Kernel 2: neighbor dot products --------------------------
__global__ __launch_bounds__(256) void scores(const float* __restrict__ qk,
                                              float* __restrict__ fwd,
                                              float* __restrict__ bwd) {
    int wave = threadIdx.x >> 6, lane = threadIdx.x & 63;
    int idx = blockIdx.x * 4 + wave;       // idx = b*SEQ + s
    int s = idx & (SEQ - 1);
    if (s == SEQ - 1) return;
    const float* row0 = qk + (size_t)idx * J2;
    const float* row1 = row0 + J2;
    float f = row0[lane] * row1[128 + lane] + row0[64 + lane] * row1[192 + lane];
    float w = row1[lane] * row0[128 + lane] + row1[64 + lane] * row0[192 + lane];
    #pragma unroll
    for (int off = 32; off; off >>= 1) {
        f += __shfl_xor(f, off);
        w += __shfl_xor(w, off);
    }
    if (lane == 0) {
        fwd[idx] = f * (1.f / 1024.f);
        bwd[idx] = w * (1.f / 1024.f);
    }
}

// ---------------- Kernel 3: softmax, neighbor_attn, log, prefix-sum --------
__global__ __launch_bounds__(1024) void neighbor(const float* __restrict__ fwd,
                                                 const float* __restrict__ bwd,
                                                 const float* __restrict__ prior,
                                                 const int* __restrict__ mask,
                                                 float* __restrict__ out_n,
                                                 float* __restrict__ csp) {
    int b = blockIdx.x, s = threadIdx.x;
    __shared__ float p1s[SEQ];
    __shared__ float buf[2][SEQ];
    int base = b << 10;
    int rolled = mask[base + ((s + 1) & (SEQ - 1))];
    float c0 = (s < SEQ - 1) ? fwd[base + s] : -INFINITY;
    if (rolled) c0 = -INFINITY;
    float c1 = (s > 0) ? bwd[base + s - 1] : -INFINITY;
    float m = fmaxf(c0, c1);
    float e0 = expf(c0 - m), e1 = expf(c1 - m);
    float inv = 1.f / (e0 + e1);
    float p0 = e0 * inv, p1 = e1 * inv;
    p1s[s] = p1;
    __syncthreads();
    float shift = (s < SEQ - 1) ? p1s[s + 1] : 0.f;   // flattened roll: next-batch p1[0]==0
    float p = sqrtf(p0 * shift + 1e-6f);
    float pr = prior[base + s];
    float na = pr + (1.f - pr) * p;
    out_n[base + s] = na;
    float lp = logf(na);
    if (rolled) lp = 0.f;
    buf[0][s] = lp;
    __syncthreads();
    int cur = 0;
    for (int off = 1; off < SEQ; off <<= 1) {
        float v = buf[cur][s];
        if (s >= off) v += buf[cur][s - off];
        buf[cur ^ 1][s] = v;
        __syncthreads();
        cur ^= 1;
    }
    csp[base + s] = (s == 0) ? 0.f : buf[cur][s - 1];   // exclusive prefix sum
}

// ---------------- Kernel 4: constituent_attn ------------------------------
__global__ __launch_bounds__(256) void outk(const float* __restrict__ csp,
                                            float* __restrict__ out) {
    int bi = blockIdx.x;                 // b*SEQ + i
    int b = bi >> 10, i = bi & (SEQ - 1);
    const float* crow = csp + (b << 10);
    float ci = crow[i];
    int t = threadIdx.x;
    float4 cj = ((const float4*)crow)[t];
    int j0 = t << 2;
    float4 r;
    {
        int j = j0 + 0;
        r.x = (j == i) ? 0.f : expf((j > i) ? (cj.x - ci) : (ci - cj.x));
        j = j0 + 1;
        r.y = (j == i) ? 0.f : expf((j > i) ? (cj.y - ci) : (ci - cj.y));
        j = j0 + 2;
        r.z = (j == i) ? 0.f : expf((j > i) ? (cj.z - ci) : (ci - cj.z));
        j = j0 + 3;
        r.w = (j == i) ? 0.f : expf((j > i) ? (cj.w - ci) : (ci - cj.w));
    }
    ((float4*)(out + (size_t)bi * SEQ))[t] = r;
}

extern "C" void kernel_launch(void* const* d_in, const int* in_sizes, int n_in,
                              void* d_out, int out_size, void* d_ws, size_t ws_size,
                              hipStream_t stream) {
    (void)in_sizes; (void)n_in; (void)out_size; (void)ws_size;
    const float* ctx   = (const float*)d_in[0];   // [S, B, E]
    const float* prior = (const float*)d_in[1];   // [B, S]
    const int*   mask  = (const int*)d_in[2];     // [B, S]
    const float* W     = (const float*)d_in[3];   // [256, 1024]
    const float* bias  = (const float*)d_in[4];   // [256]
    float* out = (float*)d_out;
    float* ws  = (float*)d_ws;

    float* qk  = ws;                              // B*S*256 floats = 33.5 MB
    float* fwd = ws + 8388608;
    float* bwd = fwd + 32768;
    float* csp = bwd + 32768;
    __hip_bfloat16* Wb = (__hip_bfloat16*)(csp + 32768);   // 256*1024 bf16
    float* out_n = out + (size_t)BATCH * SEQ * SEQ;

    convw    <<<256, 256, 0, stream>>>(W, Wb);
    gemm_mfma<<<(BATCH * SEQ / BM) * (J2 / BN), 256, 0, stream>>>(ctx, Wb, bias, qk);
    scores   <<<(BATCH * SEQ) / 4, 256, 0, stream>>>(qk, fwd, bwd);
    neighbor <<<BATCH, 1024, 0, stream>>>(fwd, bwd, prior, mask, out_n, csp);
    outk     <<<BATCH * SEQ, 256, 0, stream>>>(csp, out);
}

// Round 3
// 272.036 us; speedup vs baseline: 1.6165x; 1.0144x over previous
//
#include <hip/hip_runtime.h>
#include <hip/hip_bf16.h>
#include <math.h>

#define EMB 1024
#define BATCH 32
#define SEQ 1024
#define J2 256          // 2*PROJ
#define BM 64
#define BN 256
#define BK 64

typedef __attribute__((ext_vector_type(8))) short short8;
typedef __attribute__((ext_vector_type(4))) float f32x4;
typedef const __attribute__((address_space(1))) void gvoid;
typedef __attribute__((address_space(3))) void lvoid;

union Pack8 { short8 s; __hip_bfloat16 h[8]; };

// ---------------- Kernel 0: convert W fp32 -> bf16 -------------------------
__global__ __launch_bounds__(256) void convw(const float* __restrict__ W,
                                             __hip_bfloat16* __restrict__ Wb) {
    int i = blockIdx.x * 256 + threadIdx.x;          // 0 .. 65535, 4 floats each
    float4 v = ((const float4*)W)[i];
    __hip_bfloat16 h[4];
    h[0] = __float2bfloat16(v.x); h[1] = __float2bfloat16(v.y);
    h[2] = __float2bfloat16(v.z); h[3] = __float2bfloat16(v.w);
    *(short4*)&Wb[i * 4] = *(short4*)h;
}

// ---------------- Kernel 1: qk = ctx @ W^T + bias (bf16 MFMA) --------------
// Single pass over N: BM=64 rows (m = s*B + b), BN=256 = all output cols.
// ctx is fetched exactly once. Wave w owns n-quarter [w*64, w*64+64).
__global__ __launch_bounds__(256) void gemm_mfma(const float* __restrict__ ctx,
                                                 const __hip_bfloat16* __restrict__ Wb,
                                                 const float* __restrict__ bias,
                                                 float* __restrict__ qk) {
    __shared__ __align__(16) __hip_bfloat16 As[BM * BK];   // 8 KB, row-major
    __shared__ __align__(16) __hip_bfloat16 Bs[BN * BK];   // 32 KB
    const int t = threadIdx.x;
    const int lane = t & 63, w = t >> 6;
    const int m0 = blockIdx.x * BM;
    const int wn = w * 64;
    const int lm = lane & 15, lq = lane >> 4;

    f32x4 acc[4][4] = {};

    float bv[4];
    #pragma unroll
    for (int ni = 0; ni < 4; ni++) bv[ni] = bias[wn + ni * 16 + lm];

    const float4* ctx4 = (const float4*)ctx;

    for (int k0 = 0; k0 < EMB; k0 += BK) {
        // ---- stage B (weights): 256 rows x 64 k = 2048 x 16B, 8 per thread
        #pragma unroll
        for (int c = 0; c < 8; c++) {
            int li = c * 256 + t;                  // 16B chunk id, 0..2047
            int row = li >> 3, k8 = li & 7;
            const __hip_bfloat16* g = Wb + (size_t)row * EMB + k0 + k8 * 8;
            __hip_bfloat16* l = &Bs[(c * 256 + w * 64) * 8];  // wave-uniform base
            __builtin_amdgcn_global_load_lds((gvoid*)g, (lvoid*)l, 16, 0, 0);
        }
        // ---- stage A (ctx): fp32 load + cvt -> bf16, 64x64 = 512 chunks of 8
        const int k4 = k0 >> 2;
        #pragma unroll
        for (int c = 0; c < 2; c++) {
            int li = c * 256 + t;                  // 8-float chunk id, 0..511
            int row = li >> 3, k8 = li & 7;
            float4 v0 = ctx4[(size_t)(m0 + row) * 256 + k4 + k8 * 2];
            float4 v1 = ctx4[(size_t)(m0 + row) * 256 + k4 + k8 * 2 + 1];
            Pack8 p;
            p.h[0] = __float2bfloat16(v0.x); p.h[1] = __float2bfloat16(v0.y);
            p.h[2] = __float2bfloat16(v0.z); p.h[3] = __float2bfloat16(v0.w);
            p.h[4] = __float2bfloat16(v1.x); p.h[5] = __float2bfloat16(v1.y);
            p.h[6] = __float2bfloat16(v1.z); p.h[7] = __float2bfloat16(v1.w);
            *(short8*)&As[row * BK + k8 * 8] = p.s;
        }
        __syncthreads();
        // ---- MFMA over the two K=32 halves --------------------------------
        #pragma unroll
        for (int kk = 0; kk < BK; kk += 32) {
            short8 af[4], bfr[4];
            #pragma unroll
            for (int i = 0; i < 4; i++) {
                af[i]  = *(const short8*)&As[(i * 16 + lm) * BK + kk + lq * 8];
                bfr[i] = *(const short8*)&Bs[(wn + i * 16 + lm) * BK + kk + lq * 8];
            }
            #pragma unroll
            for (int mi = 0; mi < 4; mi++)
                #pragma unroll
                for (int ni = 0; ni < 4; ni++)
                    acc[mi][ni] = __builtin_amdgcn_mfma_f32_16x16x32_bf16(
                        af[mi], bfr[ni], acc[mi][ni], 0, 0, 0);
        }
        __syncthreads();
    }

    // ---- epilogue: D row = m (A row), col = n; add bias -------------------
    #pragma unroll
    for (int mi = 0; mi < 4; mi++) {
        #pragma unroll
        for (int r = 0; r < 4; r++) {
            int m = m0 + mi * 16 + lq * 4 + r;
            int s = m >> 5, b = m & 31;
            float* orow = qk + (size_t)((b << 10) + s) * J2;
            #pragma unroll
            for (int ni = 0; ni < 4; ni++) {
                int n = wn + ni * 16 + lm;
                orow[n] = acc[mi][ni][r] + bv[ni];
            }
        }
    }
}

// ---------------- Kernel 2: neighbor dot products --------------------------
__global__ __launch_bounds__(256) void scores(const float* __restrict__ qk,
                                              float* __restrict__ fwd,
                                              float* __restrict__ bwd) {
    int wave = threadIdx.x >> 6, lane = threadIdx.x & 63;
    int idx = blockIdx.x * 4 + wave;       // idx = b*SEQ + s
    int s = idx & (SEQ - 1);
    if (s == SEQ - 1) return;
    const float* row0 = qk + (size_t)idx * J2;
    const float* row1 = row0 + J2;
    float f = row0[lane] * row1[128 + lane] + row0[64 + lane] * row1[192 + lane];
    float w = row1[lane] * row0[128 + lane] + row1[64 + lane] * row0[192 + lane];
    #pragma unroll
    for (int off = 32; off; off >>= 1) {
        f += __shfl_xor(f, off);
        w += __shfl_xor(w, off);
    }
    if (lane == 0) {
        fwd[idx] = f * (1.f / 1024.f);
        bwd[idx] = w * (1.f / 1024.f);
    }
}

// ---------------- Kernel 3: softmax, neighbor_attn, log, prefix-sum --------
__global__ __launch_bounds__(1024) void neighbor(const float* __restrict__ fwd,
                                                 const float* __restrict__ bwd,
                                                 const float* __restrict__ prior,
                                                 const int* __restrict__ mask,
                                                 float* __restrict__ out_n,
                                                 float* __restrict__ csp) {
    int b = blockIdx.x, s = threadIdx.x;
    __shared__ float p1s[SEQ];
    __shared__ float buf[2][SEQ];
    int base = b << 10;
    int rolled = mask[base + ((s + 1) & (SEQ - 1))];
    float c0 = (s < SEQ - 1) ? fwd[base + s] : -INFINITY;
    if (rolled) c0 = -INFINITY;
    float c1 = (s > 0) ? bwd[base + s - 1] : -INFINITY;
    float m = fmaxf(c0, c1);
    float e0 = expf(c0 - m), e1 = expf(c1 - m);
    float inv = 1.f / (e0 + e1);
    float p0 = e0 * inv, p1 = e1 * inv;
    p1s[s] = p1;
    __syncthreads();
    float shift = (s < SEQ - 1) ? p1s[s + 1] : 0.f;   // flattened roll: next-batch p1[0]==0
    float p = sqrtf(p0 * shift + 1e-6f);
    float pr = prior[base + s];
    float na = pr + (1.f - pr) * p;
    out_n[base + s] = na;
    float lp = logf(na);
    if (rolled) lp = 0.f;
    buf[0][s] = lp;
    __syncthreads();
    int cur = 0;
    for (int off = 1; off < SEQ; off <<= 1) {
        float v = buf[cur][s];
        if (s >= off) v += buf[cur][s - off];
        buf[cur ^ 1][s] = v;
        __syncthreads();
        cur ^= 1;
    }
    csp[base + s] = (s == 0) ? 0.f : buf[cur][s - 1];   // exclusive prefix sum
}

// ---------------- Kernel 4: constituent_attn ------------------------------
__global__ __launch_bounds__(256) void outk(const float* __restrict__ csp,
                                            float* __restrict__ out) {
    int bi = blockIdx.x;                 // b*SEQ + i
    int b = bi >> 10, i = bi & (SEQ - 1);
    const float* crow = csp + (b << 10);
    float ci = crow[i];
    int t = threadIdx.x;
    float4 cj = ((const float4*)crow)[t];
    int j0 = t << 2;
    float4 r;
    {
        int j = j0 + 0;
        r.x = (j == i) ? 0.f : expf((j > i) ? (cj.x - ci) : (ci - cj.x));
        j = j0 + 1;
        r.y = (j == i) ? 0.f : expf((j > i) ? (cj.y - ci) : (ci - cj.y));
        j = j0 + 2;
        r.z = (j == i) ? 0.f : expf((j > i) ? (cj.z - ci) : (ci - cj.z));
        j = j0 + 3;
        r.w = (j == i) ? 0.f : expf((j > i) ? (cj.w - ci) : (ci - cj.w));
    }
    ((float4*)(out + (size_t)bi * SEQ))[t] = r;
}

extern "C" void kernel_launch(void* const* d_in, const int* in_sizes, int n_in,
                              void* d_out, int out_size, void* d_ws, size_t ws_size,
                              hipStream_t stream) {
    (void)in_sizes; (void)n_in; (void)out_size; (void)ws_size;
    const float* ctx   = (const float*)d_in[0];   // [S, B, E]
    const float* prior = (const float*)d_in[1];   // [B, S]
    const int*   mask  = (const int*)d_in[2];     // [B, S]
    const float* W     = (const float*)d_in[3];   // [256, 1024]
    const float* bias  = (const float*)d_in[4];   // [256]
    float* out = (float*)d_out;
    float* ws  = (float*)d_ws;

    float* qk  = ws;                              // B*S*256 floats = 33.5 MB
    float* fwd = ws + 8388608;
    float* bwd = fwd + 32768;
    float* csp = bwd + 32768;
    __hip_bfloat16* Wb = (__hip_bfloat16*)(csp + 32768);   // 256*1024 bf16
    float* out_n = out + (size_t)BATCH * SEQ * SEQ;

    convw    <<<256, 256, 0, stream>>>(W, Wb);
    gemm_mfma<<<(BATCH * SEQ) / BM, 256, 0, stream>>>(ctx, Wb, bias, qk);
    scores   <<<(BATCH * SEQ) / 4, 256, 0, stream>>>(qk, fwd, bwd);
    neighbor <<<BATCH, 1024, 0, stream>>>(fwd, bwd, prior, mask, out_n, csp);
    outk     <<<BATCH * SEQ, 256, 0, stream>>>(csp, out);
}

// Round 4
// 268.111 us; speedup vs baseline: 1.6402x; 1.0146x over previous
//
#include <hip/hip_runtime.h>
#include <hip/hip_bf16.h>
#include <math.h>

#define EMB 1024
#define BATCH 32
#define SEQ 1024
#define J2 256          // 2*PROJ
#define BM 64
#define BN 256
#define BK 64
#define PSEL 0x07060302u   // v_perm selector: [f1.hi16 : f0.hi16]

typedef __attribute__((ext_vector_type(8))) short short8;
typedef __attribute__((ext_vector_type(4))) float f32x4;
typedef const __attribute__((address_space(1))) void gvoid;
typedef __attribute__((address_space(3))) void lvoid;

__device__ __forceinline__ unsigned bcast(float f) {
    union { float f; unsigned u; } c; c.f = f; return c.u;
}
// pack two fp32 -> two bf16 (round-half-up) in one u32: f0 low, f1 high
__device__ __forceinline__ unsigned pack_bf16(float f0, float f1) {
    return __builtin_amdgcn_perm(bcast(f1) + 0x8000u, bcast(f0) + 0x8000u, PSEL);
}

// ---------------- Kernel 0: convert W fp32 -> bf16 -------------------------
__global__ __launch_bounds__(256) void convw(const float* __restrict__ W,
                                             __hip_bfloat16* __restrict__ Wb) {
    int i = blockIdx.x * 256 + threadIdx.x;          // 0 .. 65535, 4 floats each
    float4 v = ((const float4*)W)[i];
    __hip_bfloat16 h[4];
    h[0] = __float2bfloat16(v.x); h[1] = __float2bfloat16(v.y);
    h[2] = __float2bfloat16(v.z); h[3] = __float2bfloat16(v.w);
    *(short4*)&Wb[i * 4] = *(short4*)h;
}

// ---------------- Kernel 1: qk = ctx @ W^T + bias (bf16 MFMA) --------------
// Single pass over N: BM=64 rows (m = s*B + b), BN=256 = all output cols.
// A staged fp32->bf16 with v_perm fast pack; B staged via global_load_lds.
// Output qk in bf16, laid out qkb[((b<<10)+s)*256 + n].
__global__ __launch_bounds__(256) void gemm_mfma(const float* __restrict__ ctx,
                                                 const __hip_bfloat16* __restrict__ Wb,
                                                 const float* __restrict__ bias,
                                                 __hip_bfloat16* __restrict__ qkb) {
    __shared__ __align__(16) __hip_bfloat16 As[BM * BK];   // 8 KB, row-major
    __shared__ __align__(16) __hip_bfloat16 Bs[BN * BK];   // 32 KB
    const int t = threadIdx.x;
    const int lane = t & 63, w = t >> 6;
    const int m0 = blockIdx.x * BM;
    const int wn = w * 64;
    const int lm = lane & 15, lq = lane >> 4;

    f32x4 acc[4][4] = {};

    float bv[4];
    #pragma unroll
    for (int ni = 0; ni < 4; ni++) bv[ni] = bias[wn + ni * 16 + lm];

    const float4* ctx4 = (const float4*)ctx;

    for (int k0 = 0; k0 < EMB; k0 += BK) {
        // ---- stage B (weights): 256 rows x 64 k = 2048 x 16B, 8 per thread
        #pragma unroll
        for (int c = 0; c < 8; c++) {
            int li = c * 256 + t;                  // 16B chunk id, 0..2047
            int row = li >> 3, k8 = li & 7;
            const __hip_bfloat16* g = Wb + (size_t)row * EMB + k0 + k8 * 8;
            __hip_bfloat16* l = &Bs[(c * 256 + w * 64) * 8];  // wave-uniform base
            __builtin_amdgcn_global_load_lds((gvoid*)g, (lvoid*)l, 16, 0, 0);
        }
        // ---- stage A (ctx): fp32 load + fast pack -> bf16 LDS -------------
        const int k4 = k0 >> 2;
        #pragma unroll
        for (int c = 0; c < 2; c++) {
            int li = c * 256 + t;                  // 8-float chunk id, 0..511
            int row = li >> 3, k8 = li & 7;
            float4 v0 = ctx4[(size_t)(m0 + row) * 256 + k4 + k8 * 2];
            float4 v1 = ctx4[(size_t)(m0 + row) * 256 + k4 + k8 * 2 + 1];
            uint4 p;
            p.x = pack_bf16(v0.x, v0.y);
            p.y = pack_bf16(v0.z, v0.w);
            p.z = pack_bf16(v1.x, v1.y);
            p.w = pack_bf16(v1.z, v1.w);
            *(uint4*)&As[row * BK + k8 * 8] = p;
        }
        __syncthreads();
        // ---- MFMA over the two K=32 halves --------------------------------
        #pragma unroll
        for (int kk = 0; kk < BK; kk += 32) {
            short8 af[4], bfr[4];
            #pragma unroll
            for (int i = 0; i < 4; i++) {
                af[i]  = *(const short8*)&As[(i * 16 + lm) * BK + kk + lq * 8];
                bfr[i] = *(const short8*)&Bs[(wn + i * 16 + lm) * BK + kk + lq * 8];
            }
            #pragma unroll
            for (int mi = 0; mi < 4; mi++)
                #pragma unroll
                for (int ni = 0; ni < 4; ni++)
                    acc[mi][ni] = __builtin_amdgcn_mfma_f32_16x16x32_bf16(
                        af[mi], bfr[ni], acc[mi][ni], 0, 0, 0);
        }
        __syncthreads();
    }

    // ---- epilogue: D row = m (A row), col = n; add bias, store bf16 -------
    #pragma unroll
    for (int mi = 0; mi < 4; mi++) {
        #pragma unroll
        for (int r = 0; r < 4; r++) {
            int m = m0 + mi * 16 + lq * 4 + r;
            int s = m >> 5, b = m & 31;
            __hip_bfloat16* orow = qkb + (size_t)((b << 10) + s) * J2;
            #pragma unroll
            for (int ni = 0; ni < 4; ni++) {
                int n = wn + ni * 16 + lm;
                orow[n] = __float2bfloat16(acc[mi][ni][r] + bv[ni]);
            }
        }
    }
}

// ---------------- Kernel 2: neighbor dot products (bf16 qk) ----------------
// fwd[b,s] = q[b,s].k[b,s+1]/EMB ; bwd[b,s] = q[b,s+1].k[b,s]/EMB (s<S-1)
__global__ __launch_bounds__(256) void scores(const __hip_bfloat16* __restrict__ qkb,
                                              float* __restrict__ fwd,
                                              float* __restrict__ bwd) {
    int wave = threadIdx.x >> 6, lane = threadIdx.x & 63;
    int idx = blockIdx.x * 4 + wave;       // idx = b*SEQ + s
    int s = idx & (SEQ - 1);
    if (s == SEQ - 1) return;
    const unsigned* r0 = (const unsigned*)(qkb + (size_t)idx * J2);
    const unsigned* r1 = r0 + 128;         // next row (s+1), in u32 units
    // lane covers cols {2*lane, 2*lane+1} of q-half and k-half
    unsigned q0 = r0[lane], k0 = r0[64 + lane];
    unsigned q1 = r1[lane], k1 = r1[64 + lane];
    float2 q0f = __bfloat1622float2(*(const __hip_bfloat162*)&q0);
    float2 k0f = __bfloat1622float2(*(const __hip_bfloat162*)&k0);
    float2 q1f = __bfloat1622float2(*(const __hip_bfloat162*)&q1);
    float2 k1f = __bfloat1622float2(*(const __hip_bfloat162*)&k1);
    float f = q0f.x * k1f.x + q0f.y * k1f.y;   // q[s] . k[s+1]
    float w = q1f.x * k0f.x + q1f.y * k0f.y;   // q[s+1] . k[s]
    #pragma unroll
    for (int off = 32; off; off >>= 1) {
        f += __shfl_xor(f, off);
        w += __shfl_xor(w, off);
    }
    if (lane == 0) {
        fwd[idx] = f * (1.f / 1024.f);
        bwd[idx] = w * (1.f / 1024.f);
    }
}

// ---------------- Kernel 3: softmax, neighbor_attn, log, prefix-sum --------
__global__ __launch_bounds__(1024) void neighbor(const float* __restrict__ fwd,
                                                 const float* __restrict__ bwd,
                                                 const float* __restrict__ prior,
                                                 const int* __restrict__ mask,
                                                 float* __restrict__ out_n,
                                                 float* __restrict__ csp) {
    int b = blockIdx.x, s = threadIdx.x;
    int lane = s & 63, w = s >> 6;          // 16 waves
    __shared__ float p1s[SEQ];
    __shared__ float incl[SEQ];
    __shared__ float wsum[16];
    int base = b << 10;
    int rolled = mask[base + ((s + 1) & (SEQ - 1))];
    float c0 = (s < SEQ - 1) ? fwd[base + s] : -INFINITY;
    if (rolled) c0 = -INFINITY;
    float c1 = (s > 0) ? bwd[base + s - 1] : -INFINITY;
    float m = fmaxf(c0, c1);
    float e0 = expf(c0 - m), e1 = expf(c1 - m);
    float inv = 1.f / (e0 + e1);
    float p0 = e0 * inv, p1 = e1 * inv;
    p1s[s] = p1;
    __syncthreads();
    float shift = (s < SEQ - 1) ? p1s[s + 1] : 0.f;   // flattened roll: next-batch p1[0]==0
    float p = sqrtf(p0 * shift + 1e-6f);
    float pr = prior[base + s];
    float na = pr + (1.f - pr) * p;
    out_n[base + s] = na;
    float lp = logf(na);
    if (rolled) lp = 0.f;
    // wave-level inclusive scan (6 shuffle steps, no barriers)
    float x = lp;
    #pragma unroll
    for (int off = 1; off < 64; off <<= 1) {
        float v = __shfl_up(x, off);
        if (lane >= off) x += v;
    }
    if (lane == 63) wsum[w] = x;
    __syncthreads();
    if (w == 0) {
        float v = (lane < 16) ? wsum[lane] : 0.f;
        #pragma unroll
        for (int off = 1; off < 16; off <<= 1) {
            float t2 = __shfl_up(v, off);
            if (lane >= off) v += t2;
        }
        if (lane < 16) wsum[lane] = v;
    }
    __syncthreads();
    float woff = (w > 0) ? wsum[w - 1] : 0.f;
    incl[s] = x + woff;
    __syncthreads();
    csp[base + s] = (s == 0) ? 0.f : incl[s - 1];   // exclusive prefix sum
}

// ---------------- Kernel 4: constituent_attn ------------------------------
__global__ __launch_bounds__(256) void outk(const float* __restrict__ csp,
                                            float* __restrict__ out) {
    int bi = blockIdx.x;                 // b*SEQ + i
    int b = bi >> 10, i = bi & (SEQ - 1);
    const float* crow = csp + (b << 10);
    float ci = crow[i];
    int t = threadIdx.x;
    float4 cj = ((const float4*)crow)[t];
    int j0 = t << 2;
    float4 r;
    {
        int j = j0 + 0;
        r.x = (j == i) ? 0.f : expf((j > i) ? (cj.x - ci) : (ci - cj.x));
        j = j0 + 1;
        r.y = (j == i) ? 0.f : expf((j > i) ? (cj.y - ci) : (ci - cj.y));
        j = j0 + 2;
        r.z = (j == i) ? 0.f : expf((j > i) ? (cj.z - ci) : (ci - cj.z));
        j = j0 + 3;
        r.w = (j == i) ? 0.f : expf((j > i) ? (cj.w - ci) : (ci - cj.w));
    }
    ((float4*)(out + (size_t)bi * SEQ))[t] = r;
}

extern "C" void kernel_launch(void* const* d_in, const int* in_sizes, int n_in,
                              void* d_out, int out_size, void* d_ws, size_t ws_size,
                              hipStream_t stream) {
    (void)in_sizes; (void)n_in; (void)out_size; (void)ws_size;
    const float* ctx   = (const float*)d_in[0];   // [S, B, E]
    const float* prior = (const float*)d_in[1];   // [B, S]
    const int*   mask  = (const int*)d_in[2];     // [B, S]
    const float* W     = (const float*)d_in[3];   // [256, 1024]
    const float* bias  = (const float*)d_in[4];   // [256]
    float* out = (float*)d_out;
    float* ws  = (float*)d_ws;

    __hip_bfloat16* qkb = (__hip_bfloat16*)ws;    // B*S*256 bf16 = 16.7 MB
    float* fwd = ws + 4194304;
    float* bwd = fwd + 32768;
    float* csp = bwd + 32768;
    __hip_bfloat16* Wb = (__hip_bfloat16*)(csp + 32768);   // 256*1024 bf16
    float* out_n = out + (size_t)BATCH * SEQ * SEQ;

    convw    <<<256, 256, 0, stream>>>(W, Wb);
    gemm_mfma<<<(BATCH * SEQ) / BM, 256, 0, stream>>>(ctx, Wb, bias, qkb);
    scores   <<<(BATCH * SEQ) / 4, 256, 0, stream>>>(qkb, fwd, bwd);
    neighbor <<<BATCH, 1024, 0, stream>>>(fwd, bwd, prior, mask, out_n, csp);
    outk     <<<BATCH * SEQ, 256, 0, stream>>>(csp, out);
}